// Round 1
// baseline (6434.487 us; speedup 1.0000x reference)
//
#include <hip/hip_runtime.h>
#include <hip/hip_bf16.h>

#define Sdim 1024
#define Bdim 8
#define Edim 512
#define Hdim 8
#define Ddim 64
#define Ndim 64   // B*H
#define Mdim 8192 // S*B

// ---------------------------------------------------------------------------
// Mask dtype detector: if the bool mask was uploaded as raw bytes, viewing it
// as int32 gives values outside {0,1} almost surely within 4096 words.
// flag = 1 -> byte mask, flag = 0 -> int32 mask.
// ---------------------------------------------------------------------------
__global__ void detect_mask(const unsigned int* __restrict__ m, int* __restrict__ flag) {
    __shared__ int s_any;
    if (threadIdx.x == 0) s_any = 0;
    __syncthreads();
    int bad = 0;
    for (int i = threadIdx.x; i < 4096; i += blockDim.x)
        if (m[i] > 1u) bad = 1;
    if (bad) s_any = 1;  // benign race
    __syncthreads();
    if (threadIdx.x == 0) *flag = s_any;
}

// ---------------------------------------------------------------------------
// Tiled fp32 GEMM: C[m,o] = sum_k A[m,k]*W[o,k] + bias[o]  (x @ W.T + b)
// MODE 0: scatter outputs to [n, s, d] layout (n = b*H + h, from m=(s,b), o=(h,d))
// MODE 1: plain [m, o] output + residual add
// BM=BN=64, BK=16, 256 threads, 4x4 micro-tile.
// ---------------------------------------------------------------------------
template <int MODE>
__global__ __launch_bounds__(256) void proj_gemm(const float* __restrict__ A,
                                                 const float* __restrict__ W,
                                                 const float* __restrict__ bias,
                                                 const float* __restrict__ res,
                                                 float* __restrict__ out) {
    __shared__ float As[16][68];
    __shared__ float Ws[16][68];
    const int t = threadIdx.x;
    const int tx = t & 15, ty = t >> 4;
    const int m0 = blockIdx.x * 64;
    const int n0 = blockIdx.y * 64;
    float acc[4][4] = {};
    const int lr = t >> 2;       // row within 64-tile
    const int lk = (t & 3) * 4;  // k offset (float4)
    for (int k0 = 0; k0 < Edim; k0 += 16) {
        const float4 av = *(const float4*)(A + (size_t)(m0 + lr) * Edim + k0 + lk);
        const float4 wv = *(const float4*)(W + (size_t)(n0 + lr) * Edim + k0 + lk);
        As[lk + 0][lr] = av.x; As[lk + 1][lr] = av.y; As[lk + 2][lr] = av.z; As[lk + 3][lr] = av.w;
        Ws[lk + 0][lr] = wv.x; Ws[lk + 1][lr] = wv.y; Ws[lk + 2][lr] = wv.z; Ws[lk + 3][lr] = wv.w;
        __syncthreads();
#pragma unroll
        for (int kk = 0; kk < 16; ++kk) {
            float a[4], b[4];
#pragma unroll
            for (int ii = 0; ii < 4; ++ii) a[ii] = As[kk][ty + 16 * ii];
#pragma unroll
            for (int jj = 0; jj < 4; ++jj) b[jj] = Ws[kk][tx + 16 * jj];
#pragma unroll
            for (int ii = 0; ii < 4; ++ii)
#pragma unroll
                for (int jj = 0; jj < 4; ++jj) acc[ii][jj] += a[ii] * b[jj];
        }
        __syncthreads();
    }
#pragma unroll
    for (int ii = 0; ii < 4; ++ii) {
        const int m = m0 + ty + 16 * ii;
#pragma unroll
        for (int jj = 0; jj < 4; ++jj) {
            const int o = n0 + tx + 16 * jj;
            float v = acc[ii][jj] + bias[o];
            if (MODE == 0) {
                const int s = m / Bdim, b = m % Bdim;
                const int h = o >> 6, d = o & 63;
                out[(((size_t)(b * Hdim + h) * Sdim) + s) * Ddim + d] = v;
            } else {
                out[(size_t)m * Edim + o] = v + res[(size_t)m * Edim + o];
            }
        }
    }
}

// ---------------------------------------------------------------------------
// Logits: attn[n,i,j] = 0.125*( q[n,i,:].k[n,j,:] + ek[j,i,:].q[n,j,:] ),
// masked -> -3e38.  Block = (n, 16 i's, 64 j's); grid.x = n (fastest) so the
// 64 head-blocks sharing an edge_key tile hit L2/L3.
// ---------------------------------------------------------------------------
__global__ __launch_bounds__(256) void logits_kernel(const float* __restrict__ q,
                                                     const float* __restrict__ k,
                                                     const float* __restrict__ ek,
                                                     const unsigned char* __restrict__ mask8,
                                                     const int* __restrict__ flag,
                                                     float* __restrict__ attn) {
    __shared__ float Qi[16][65];
    __shared__ float Kj[64][65];
    __shared__ float Qj[64][65];
    const int n = blockIdx.x;
    const int i0 = blockIdx.y * 16;
    const int j0 = blockIdx.z * 64;
    const int t = threadIdx.x;
    const int tj = t & 63, tq = t >> 6;
    {
        const int r = t >> 4, c = (t & 15) * 4;
        const float4 v = *(const float4*)(q + (size_t)(n * Sdim + i0 + r) * Ddim + c);
        Qi[r][c] = v.x; Qi[r][c + 1] = v.y; Qi[r][c + 2] = v.z; Qi[r][c + 3] = v.w;
    }
#pragma unroll
    for (int rr = 0; rr < 4; ++rr) {
        const int r = (t >> 4) + rr * 16, c = (t & 15) * 4;
        const float4 kv = *(const float4*)(k + (size_t)(n * Sdim + j0 + r) * Ddim + c);
        Kj[r][c] = kv.x; Kj[r][c + 1] = kv.y; Kj[r][c + 2] = kv.z; Kj[r][c + 3] = kv.w;
        const float4 qv = *(const float4*)(q + (size_t)(n * Sdim + j0 + r) * Ddim + c);
        Qj[r][c] = qv.x; Qj[r][c + 1] = qv.y; Qj[r][c + 2] = qv.z; Qj[r][c + 3] = qv.w;
    }
    __syncthreads();
    float accq[4] = {}, accb[4] = {};
    const float4* ekp[4];
#pragma unroll
    for (int isub = 0; isub < 4; ++isub) {
        const int il = tq + 4 * isub;
        ekp[isub] = (const float4*)(ek + ((size_t)(j0 + tj) * Sdim + (i0 + il)) * Ddim);
    }
#pragma unroll
    for (int dv = 0; dv < 16; ++dv) {
        float4 ev[4];
        ev[0] = ekp[0][dv]; ev[1] = ekp[1][dv]; ev[2] = ekp[2][dv]; ev[3] = ekp[3][dv];
        const float* evf = (const float*)ev;
#pragma unroll
        for (int e = 0; e < 4; ++e) {
            const int d = dv * 4 + e;
            const float kj = Kj[tj][d];
            const float qj = Qj[tj][d];
#pragma unroll
            for (int isub = 0; isub < 4; ++isub) {
                accq[isub] += Qi[tq + 4 * isub][d] * kj;
                accb[isub] += evf[isub * 4 + e] * qj;
            }
        }
    }
    const bool bmode = (*flag != 0);
#pragma unroll
    for (int isub = 0; isub < 4; ++isub) {
        const int i = i0 + tq + 4 * isub;
        const size_t f = ((size_t)n * Sdim + i) * Sdim + (j0 + tj);
        const bool msk = bmode ? (mask8[f] != 0) : (((const int*)mask8)[f] != 0);
        const float v = (accq[isub] + accb[isub]) * 0.125f;
        attn[f] = msk ? -3.0e38f : v;
    }
}

// ---------------------------------------------------------------------------
// Row softmax over j (1024 elems), one block per (n,i) row.
// ---------------------------------------------------------------------------
__global__ __launch_bounds__(256) void softmax_kernel(float* __restrict__ attn) {
    const size_t base = (size_t)blockIdx.x * Sdim;
    const int t = threadIdx.x;
    float4 x = *(const float4*)(attn + base + t * 4);
    float m = fmaxf(fmaxf(x.x, x.y), fmaxf(x.z, x.w));
#pragma unroll
    for (int off = 32; off > 0; off >>= 1) m = fmaxf(m, __shfl_down(m, off));
    __shared__ float red[4];
    __shared__ float red2[4];
    if ((t & 63) == 0) red[t >> 6] = m;
    __syncthreads();
    m = fmaxf(fmaxf(red[0], red[1]), fmaxf(red[2], red[3]));
    x.x = __expf(x.x - m); x.y = __expf(x.y - m);
    x.z = __expf(x.z - m); x.w = __expf(x.w - m);
    float s = x.x + x.y + x.z + x.w;
#pragma unroll
    for (int off = 32; off > 0; off >>= 1) s += __shfl_down(s, off);
    if ((t & 63) == 0) red2[t >> 6] = s;
    __syncthreads();
    s = red2[0] + red2[1] + red2[2] + red2[3];
    const float inv = (s > 0.0f) ? (1.0f / s) : 0.0f;
    x.x *= inv; x.y *= inv; x.z *= inv; x.w *= inv;
    *(float4*)(attn + base + t * 4) = x;
}

// ---------------------------------------------------------------------------
// out[n,i,d] = sum_j P[n,i,j]*(v[n,j,d] + ev[i,j,d]); write into context
// layout ctx[(s*B+b)*E + h*64 + d].  Block = (n, 16 i's); lane = d.
// grid.x = n fastest so head-blocks sharing an edge_value slice hit L2/L3.
// ---------------------------------------------------------------------------
__global__ __launch_bounds__(256) void pv_kernel(const float* __restrict__ attn,
                                                 const float* __restrict__ v,
                                                 const float* __restrict__ evl,
                                                 float* __restrict__ ctx) {
    __shared__ float Ps[16][65];
    const int n = blockIdx.x;
    const int i0 = blockIdx.y * 16;
    const int t = threadIdx.x;
    const int td = t & 63, tq = t >> 6;
    float acc[4] = {};
    for (int j0 = 0; j0 < Sdim; j0 += 64) {
        {
            const int r = t >> 4, c = (t & 15) * 4;
            const float4 p = *(const float4*)(attn + ((size_t)n * Sdim + i0 + r) * Sdim + j0 + c);
            Ps[r][c] = p.x; Ps[r][c + 1] = p.y; Ps[r][c + 2] = p.z; Ps[r][c + 3] = p.w;
        }
        __syncthreads();
#pragma unroll 4
        for (int jj = 0; jj < 64; ++jj) {
            const int j = j0 + jj;
            const float vv = v[(size_t)(n * Sdim + j) * Ddim + td];
#pragma unroll
            for (int isub = 0; isub < 4; ++isub) {
                const int il = tq + 4 * isub;
                const float p = Ps[il][jj];
                const float ee = evl[((size_t)(i0 + il) * Sdim + j) * Ddim + td];
                acc[isub] += p * (vv + ee);
            }
        }
        __syncthreads();
    }
    const int b = n >> 3, h = n & 7;
#pragma unroll
    for (int isub = 0; isub < 4; ++isub) {
        const int s = i0 + tq + 4 * isub;
        ctx[((size_t)(s * Bdim + b) * Edim) + h * Ddim + td] = acc[isub];
    }
}

// ---------------------------------------------------------------------------
// LayerNorm over last dim (512), in place on x (= d_out).
// ---------------------------------------------------------------------------
__global__ __launch_bounds__(256) void ln_kernel(float* __restrict__ x,
                                                 const float* __restrict__ gamma,
                                                 const float* __restrict__ beta) {
    const int m = blockIdx.x;
    const int t = threadIdx.x;
    float2 v = *(const float2*)(x + (size_t)m * Edim + t * 2);
    float s = v.x + v.y;
    float ss = v.x * v.x + v.y * v.y;
#pragma unroll
    for (int off = 32; off > 0; off >>= 1) {
        s += __shfl_down(s, off);
        ss += __shfl_down(ss, off);
    }
    __shared__ float rs[4], rss[4];
    if ((t & 63) == 0) { rs[t >> 6] = s; rss[t >> 6] = ss; }
    __syncthreads();
    s = rs[0] + rs[1] + rs[2] + rs[3];
    ss = rss[0] + rss[1] + rss[2] + rss[3];
    const float mean = s * (1.0f / Edim);
    const float var = ss * (1.0f / Edim) - mean * mean;
    const float rstd = rsqrtf(var + 1e-5f);
    const int o = t * 2;
    const float2 g = *(const float2*)(gamma + o);
    const float2 bb = *(const float2*)(beta + o);
    float2 out;
    out.x = g.x * (v.x - mean) * rstd + bb.x;
    out.y = g.y * (v.y - mean) * rstd + bb.y;
    *(float2*)(x + (size_t)m * Edim + o) = out;
}

extern "C" void kernel_launch(void* const* d_in, const int* in_sizes, int n_in,
                              void* d_out, int out_size, void* d_ws, size_t ws_size,
                              hipStream_t stream) {
    const float* query = (const float*)d_in[0];
    const float* key = (const float*)d_in[1];
    const float* value = (const float*)d_in[2];
    const float* ek = (const float*)d_in[3];
    const float* evl = (const float*)d_in[4];
    const unsigned char* mask = (const unsigned char*)d_in[5];
    const float* Wq = (const float*)d_in[7];
    const float* bq = (const float*)d_in[8];
    const float* Wk = (const float*)d_in[9];
    const float* bk = (const float*)d_in[10];
    const float* Wv = (const float*)d_in[11];
    const float* bv = (const float*)d_in[12];
    const float* Wo = (const float*)d_in[13];
    const float* bo = (const float*)d_in[14];
    const float* gamma = (const float*)d_in[15];
    const float* beta = (const float*)d_in[16];

    float* ws = (float*)d_ws;
    const size_t nsd = (size_t)Ndim * Sdim * Ddim;  // 4,194,304
    float* qb = ws;
    float* kb = qb + nsd;
    float* vb = kb + nsd;
    float* attn = vb + nsd;
    int* flag = (int*)(attn + (size_t)Ndim * Sdim * Sdim);
    float* ctx = qb;  // reuse q buffer after logits has consumed it
    float* xb = (float*)d_out;

    detect_mask<<<1, 256, 0, stream>>>((const unsigned int*)mask, flag);

    dim3 gp(Mdim / 64, Edim / 64);
    proj_gemm<0><<<gp, 256, 0, stream>>>(query, Wq, bq, nullptr, qb);
    proj_gemm<0><<<gp, 256, 0, stream>>>(key, Wk, bk, nullptr, kb);
    proj_gemm<0><<<gp, 256, 0, stream>>>(value, Wv, bv, nullptr, vb);

    logits_kernel<<<dim3(Ndim, Sdim / 16, Sdim / 64), 256, 0, stream>>>(qb, kb, ek, mask, flag, attn);
    softmax_kernel<<<dim3(Ndim * Sdim), 256, 0, stream>>>(attn);
    pv_kernel<<<dim3(Ndim, Sdim / 16), 256, 0, stream>>>(attn, vb, evl, ctx);

    proj_gemm<1><<<gp, 256, 0, stream>>>(ctx, Wo, bo, query, xb);
    ln_kernel<<<dim3(Mdim), 256, 0, stream>>>(xb, gamma, beta);
}

// Round 2
// 3081.275 us; speedup vs baseline: 2.0883x; 2.0883x over previous
//
#include <hip/hip_runtime.h>

#define Sdim 1024
#define Bdim 8
#define Edim 512
#define Hdim 8
#define Ddim 64
#define Ndim 64   // B*H
#define Mdim 8192 // S*B

typedef __attribute__((ext_vector_type(8))) short short8;  // 8 bf16 = 4 VGPRs (MFMA A/B frag)
typedef __attribute__((ext_vector_type(4))) float f32x4;   // MFMA C/D frag

__device__ inline unsigned short f2bf(float x) {  // RNE float->bf16 (finite inputs)
    unsigned int u = __float_as_uint(x);
    u += 0x7FFFu + ((u >> 16) & 1u);
    return (unsigned short)(u >> 16);
}

// ---------------------------------------------------------------------------
// Mask dtype detector: byte-packed bools viewed as int32 give values >1.
// flag = 1 -> byte mask, 0 -> int32 mask.
// ---------------------------------------------------------------------------
__global__ void detect_mask(const unsigned int* __restrict__ m, int* __restrict__ flag) {
    __shared__ int s_any;
    if (threadIdx.x == 0) s_any = 0;
    __syncthreads();
    int bad = 0;
    for (int i = threadIdx.x; i < 4096; i += blockDim.x)
        if (m[i] > 1u) bad = 1;
    if (bad) s_any = 1;
    __syncthreads();
    if (threadIdx.x == 0) *flag = s_any;
}

// ---------------------------------------------------------------------------
// Tiled fp32 GEMM: C[m,o] = sum_k A[m,k]*W[o,k] + bias[o]
// MODE 0: bf16 output scattered to [n,s,d]   (q,k for MFMA logits)
// MODE 2: fp32 output scattered to [n,s,d]   (v)
// MODE 1: fp32 [m,o] output + residual add   (out proj)
// ---------------------------------------------------------------------------
template <int MODE>
__global__ __launch_bounds__(256) void proj_gemm(const float* __restrict__ A,
                                                 const float* __restrict__ W,
                                                 const float* __restrict__ bias,
                                                 const float* __restrict__ res,
                                                 void* __restrict__ outv) {
    __shared__ float As[16][68];
    __shared__ float Ws[16][68];
    const int t = threadIdx.x;
    const int tx = t & 15, ty = t >> 4;
    const int m0 = blockIdx.x * 64;
    const int n0 = blockIdx.y * 64;
    float acc[4][4] = {};
    const int lr = t >> 2;
    const int lk = (t & 3) * 4;
    for (int k0 = 0; k0 < Edim; k0 += 16) {
        const float4 av = *(const float4*)(A + (size_t)(m0 + lr) * Edim + k0 + lk);
        const float4 wv = *(const float4*)(W + (size_t)(n0 + lr) * Edim + k0 + lk);
        As[lk + 0][lr] = av.x; As[lk + 1][lr] = av.y; As[lk + 2][lr] = av.z; As[lk + 3][lr] = av.w;
        Ws[lk + 0][lr] = wv.x; Ws[lk + 1][lr] = wv.y; Ws[lk + 2][lr] = wv.z; Ws[lk + 3][lr] = wv.w;
        __syncthreads();
#pragma unroll
        for (int kk = 0; kk < 16; ++kk) {
            float a[4], b[4];
#pragma unroll
            for (int ii = 0; ii < 4; ++ii) a[ii] = As[kk][ty + 16 * ii];
#pragma unroll
            for (int jj = 0; jj < 4; ++jj) b[jj] = Ws[kk][tx + 16 * jj];
#pragma unroll
            for (int ii = 0; ii < 4; ++ii)
#pragma unroll
                for (int jj = 0; jj < 4; ++jj) acc[ii][jj] += a[ii] * b[jj];
        }
        __syncthreads();
    }
#pragma unroll
    for (int ii = 0; ii < 4; ++ii) {
        const int m = m0 + ty + 16 * ii;
#pragma unroll
        for (int jj = 0; jj < 4; ++jj) {
            const int o = n0 + tx + 16 * jj;
            float v = acc[ii][jj] + bias[o];
            if (MODE == 1) {
                ((float*)outv)[(size_t)m * Edim + o] = v + res[(size_t)m * Edim + o];
            } else {
                const int s = m / Bdim, b = m % Bdim;
                const int h = o >> 6, d = o & 63;
                const size_t f = (((size_t)(b * Hdim + h) * Sdim) + s) * Ddim + d;
                if (MODE == 0) ((unsigned short*)outv)[f] = f2bf(v);
                else           ((float*)outv)[f] = v;
            }
        }
    }
}

// ---------------------------------------------------------------------------
// MFMA logits: attn[n,i,j] = 0.125*(qk + bias), masked -> -3e38.
//   qk:   per n, mfma D[i,j]  = sum_d qh[n,i,d]*kh[n,j,d]
//   bias: per j, mfma D[i,n]  = sum_d ek[j,i,d]*qh[n,j,d]
// Block = (i-tile 16) x (j-tile 16), loops all 64 n in 4 groups of 16.
// ek tile is held in REGISTERS as bf16 A-frags across the n-loop (loaded once
// from HBM -> exactly 268 MB ek traffic, no L2-sharing assumption).
// Bias MFMA output (lanes = n) is transposed to qk layout (lanes = j) via a
// padded LDS buffer.
// Frag layouts (HW-verified, guide §3): A/B[row=lane&15][k=quad*8+e],
// C/D: col=lane&15, row=quad*4+reg.
// ---------------------------------------------------------------------------
__global__ __launch_bounds__(256) void logits_mfma(const unsigned short* __restrict__ qh,
                                                   const unsigned short* __restrict__ kh,
                                                   const float* __restrict__ ek,
                                                   const unsigned char* __restrict__ mask8,
                                                   const int* __restrict__ flag,
                                                   float* __restrict__ attn) {
    // bias_s[i_local][j_local][n_local], addr = i*273 + j*17 + n (pads kill conflicts)
    __shared__ float bias_s[16 * 273 + 16];
    const int t = threadIdx.x;
    const int wave = t >> 6, lane = t & 63;
    const int quad = lane >> 4, l15 = lane & 15;
    const int i0 = blockIdx.y * 16;
    const int j0 = blockIdx.x * 16;
    const bool bmode = (*flag != 0);

    // Phase 0: load ek tile -> bf16 A-frags in registers (4 j's per wave x 2 K-halves)
    short8 ekf[4][2];
#pragma unroll
    for (int jj = 0; jj < 4; ++jj) {
        const int j = j0 + wave * 4 + jj;
#pragma unroll
        for (int kk = 0; kk < 2; ++kk) {
            const float4* p = (const float4*)(ek + ((size_t)j * Sdim + (i0 + l15)) * Ddim + kk * 32 + quad * 8);
            const float4 x = p[0], y = p[1];
            short8 f;
            f[0] = (short)f2bf(x.x); f[1] = (short)f2bf(x.y);
            f[2] = (short)f2bf(x.z); f[3] = (short)f2bf(x.w);
            f[4] = (short)f2bf(y.x); f[5] = (short)f2bf(y.y);
            f[6] = (short)f2bf(y.z); f[7] = (short)f2bf(y.w);
            ekf[jj][kk] = f;
        }
    }

    for (int n0 = 0; n0 < Ndim; n0 += 16) {
        // Phase 1: bias MFMA. A = ek frag (m=i), B = qh[n0+l15][j][:] (nn=n).
#pragma unroll
        for (int jj = 0; jj < 4; ++jj) {
            const int j = j0 + wave * 4 + jj;
            f32x4 acc = {0.f, 0.f, 0.f, 0.f};
#pragma unroll
            for (int kk = 0; kk < 2; ++kk) {
                const short8 b = *(const short8*)(qh + ((size_t)(n0 + l15) * Sdim + j) * Ddim + kk * 32 + quad * 8);
                acc = __builtin_amdgcn_mfma_f32_16x16x32_bf16(ekf[jj][kk], b, acc, 0, 0, 0);
            }
            const int jl = wave * 4 + jj;
#pragma unroll
            for (int r = 0; r < 4; ++r)
                bias_s[(quad * 4 + r) * 273 + jl * 17 + l15] = acc[r];
        }
        __syncthreads();
        // Phase 2: qk MFMA (A = qh rows m=i, B = kh rows nn=j) + combine + mask + store.
#pragma unroll
        for (int nn = 0; nn < 4; ++nn) {
            const int nl = wave * 4 + nn;
            const int n = n0 + nl;
            f32x4 acc = {0.f, 0.f, 0.f, 0.f};
#pragma unroll
            for (int kk = 0; kk < 2; ++kk) {
                const short8 a = *(const short8*)(qh + ((size_t)n * Sdim + (i0 + l15)) * Ddim + kk * 32 + quad * 8);
                const short8 b = *(const short8*)(kh + ((size_t)n * Sdim + (j0 + l15)) * Ddim + kk * 32 + quad * 8);
                acc = __builtin_amdgcn_mfma_f32_16x16x32_bf16(a, b, acc, 0, 0, 0);
            }
#pragma unroll
            for (int r = 0; r < 4; ++r) {
                const int il = quad * 4 + r;
                const int i = i0 + il;
                const int j = j0 + l15;
                const float bias = bias_s[il * 273 + l15 * 17 + nl];
                const size_t f = ((size_t)n * Sdim + i) * Sdim + j;
                const bool msk = bmode ? (mask8[f] != 0) : (((const int*)mask8)[f] != 0);
                const float v = (acc[r] + bias) * 0.125f;
                attn[f] = msk ? -3.0e38f : v;
            }
        }
        __syncthreads();  // bias_s reused by next n-group
    }
}

// ---------------------------------------------------------------------------
// Row softmax over j (1024), one block per (n,i) row.
// ---------------------------------------------------------------------------
__global__ __launch_bounds__(256) void softmax_kernel(float* __restrict__ attn) {
    const size_t base = (size_t)blockIdx.x * Sdim;
    const int t = threadIdx.x;
    float4 x = *(const float4*)(attn + base + t * 4);
    float m = fmaxf(fmaxf(x.x, x.y), fmaxf(x.z, x.w));
#pragma unroll
    for (int off = 32; off > 0; off >>= 1) m = fmaxf(m, __shfl_down(m, off));
    __shared__ float red[4];
    __shared__ float red2[4];
    if ((t & 63) == 0) red[t >> 6] = m;
    __syncthreads();
    m = fmaxf(fmaxf(red[0], red[1]), fmaxf(red[2], red[3]));
    x.x = __expf(x.x - m); x.y = __expf(x.y - m);
    x.z = __expf(x.z - m); x.w = __expf(x.w - m);
    float s = x.x + x.y + x.z + x.w;
#pragma unroll
    for (int off = 32; off > 0; off >>= 1) s += __shfl_down(s, off);
    if ((t & 63) == 0) red2[t >> 6] = s;
    __syncthreads();
    s = red2[0] + red2[1] + red2[2] + red2[3];
    const float inv = (s > 0.0f) ? (1.0f / s) : 0.0f;
    x.x *= inv; x.y *= inv; x.z *= inv; x.w *= inv;
    *(float4*)(attn + base + t * 4) = x;
}

// ---------------------------------------------------------------------------
// out[n,i,d] = sum_j P[n,i,j]*(v[n,j,d] + ev[i,j,d]); write ctx[(s*B+b)*E+h*64+d]
// ---------------------------------------------------------------------------
__global__ __launch_bounds__(256) void pv_kernel(const float* __restrict__ attn,
                                                 const float* __restrict__ v,
                                                 const float* __restrict__ evl,
                                                 float* __restrict__ ctx) {
    __shared__ float Ps[16][65];
    const int n = blockIdx.x;
    const int i0 = blockIdx.y * 16;
    const int t = threadIdx.x;
    const int td = t & 63, tq = t >> 6;
    float acc[4] = {};
    for (int j0 = 0; j0 < Sdim; j0 += 64) {
        {
            const int r = t >> 4, c = (t & 15) * 4;
            const float4 p = *(const float4*)(attn + ((size_t)n * Sdim + i0 + r) * Sdim + j0 + c);
            Ps[r][c] = p.x; Ps[r][c + 1] = p.y; Ps[r][c + 2] = p.z; Ps[r][c + 3] = p.w;
        }
        __syncthreads();
#pragma unroll 4
        for (int jj = 0; jj < 64; ++jj) {
            const int j = j0 + jj;
            const float vv = v[(size_t)(n * Sdim + j) * Ddim + td];
#pragma unroll
            for (int isub = 0; isub < 4; ++isub) {
                const int il = tq + 4 * isub;
                const float p = Ps[il][jj];
                const float ee = evl[((size_t)(i0 + il) * Sdim + j) * Ddim + td];
                acc[isub] += p * (vv + ee);
            }
        }
        __syncthreads();
    }
    const int b = n >> 3, h = n & 7;
#pragma unroll
    for (int isub = 0; isub < 4; ++isub) {
        const int s = i0 + tq + 4 * isub;
        ctx[((size_t)(s * Bdim + b) * Edim) + h * Ddim + td] = acc[isub];
    }
}

// ---------------------------------------------------------------------------
// LayerNorm over last dim (512), in place on x (= d_out).
// ---------------------------------------------------------------------------
__global__ __launch_bounds__(256) void ln_kernel(float* __restrict__ x,
                                                 const float* __restrict__ gamma,
                                                 const float* __restrict__ beta) {
    const int m = blockIdx.x;
    const int t = threadIdx.x;
    float2 v = *(const float2*)(x + (size_t)m * Edim + t * 2);
    float s = v.x + v.y;
    float ss = v.x * v.x + v.y * v.y;
#pragma unroll
    for (int off = 32; off > 0; off >>= 1) {
        s += __shfl_down(s, off);
        ss += __shfl_down(ss, off);
    }
    __shared__ float rs[4], rss[4];
    if ((t & 63) == 0) { rs[t >> 6] = s; rss[t >> 6] = ss; }
    __syncthreads();
    s = rs[0] + rs[1] + rs[2] + rs[3];
    ss = rss[0] + rss[1] + rss[2] + rss[3];
    const float mean = s * (1.0f / Edim);
    const float var = ss * (1.0f / Edim) - mean * mean;
    const float rstd = rsqrtf(var + 1e-5f);
    const int o = t * 2;
    const float2 g = *(const float2*)(gamma + o);
    const float2 bb = *(const float2*)(beta + o);
    float2 out;
    out.x = g.x * (v.x - mean) * rstd + bb.x;
    out.y = g.y * (v.y - mean) * rstd + bb.y;
    *(float2*)(x + (size_t)m * Edim + o) = out;
}

extern "C" void kernel_launch(void* const* d_in, const int* in_sizes, int n_in,
                              void* d_out, int out_size, void* d_ws, size_t ws_size,
                              hipStream_t stream) {
    const float* query = (const float*)d_in[0];
    const float* key = (const float*)d_in[1];
    const float* value = (const float*)d_in[2];
    const float* ek = (const float*)d_in[3];
    const float* evl = (const float*)d_in[4];
    const unsigned char* mask = (const unsigned char*)d_in[5];
    const float* Wq = (const float*)d_in[7];
    const float* bq = (const float*)d_in[8];
    const float* Wk = (const float*)d_in[9];
    const float* bk = (const float*)d_in[10];
    const float* Wv = (const float*)d_in[11];
    const float* bv = (const float*)d_in[12];
    const float* Wo = (const float*)d_in[13];
    const float* bo = (const float*)d_in[14];
    const float* gamma = (const float*)d_in[15];
    const float* beta = (const float*)d_in[16];

    const size_t nsd = (size_t)Ndim * Sdim * Ddim;  // 4,194,304
    unsigned short* qh = (unsigned short*)d_ws;     // bf16 [n][s][d]
    unsigned short* kh = qh + nsd;                  // bf16 [n][s][d]
    float* vb = (float*)(kh + nsd);                 // fp32 [n][s][d]
    float* ctx = vb + nsd;                          // fp32 [s*B][E]
    float* attn = ctx + nsd;                        // fp32 [n][i][j]
    int* flag = (int*)(attn + (size_t)Ndim * Sdim * Sdim);
    float* xb = (float*)d_out;

    detect_mask<<<1, 256, 0, stream>>>((const unsigned int*)mask, flag);

    dim3 gp(Mdim / 64, Edim / 64);
    proj_gemm<0><<<gp, 256, 0, stream>>>(query, Wq, bq, nullptr, qh);
    proj_gemm<0><<<gp, 256, 0, stream>>>(key, Wk, bk, nullptr, kh);
    proj_gemm<2><<<gp, 256, 0, stream>>>(value, Wv, bv, nullptr, vb);

    logits_mfma<<<dim3(Sdim / 16, Sdim / 16), 256, 0, stream>>>(qh, kh, ek, mask, flag, attn);
    softmax_kernel<<<dim3(Ndim * Sdim), 256, 0, stream>>>(attn);
    pv_kernel<<<dim3(Ndim, Sdim / 16), 256, 0, stream>>>(attn, vb, evl, ctx);

    proj_gemm<1><<<gp, 256, 0, stream>>>(ctx, Wo, bo, query, xb);
    ln_kernel<<<dim3(Mdim), 256, 0, stream>>>(xb, gamma, beta);
}